// Round 15
// baseline (61.786 us; speedup 1.0000x reference)
//
#include <hip/hip_runtime.h>
#include <hip/hip_bf16.h>
#include <math.h>

// signs c1,c2 decoded in round 0/1: both +1 (absmax 0.0078 = bf16 noise)
#define C1 1.0f
#define C2 1.0f

static constexpr float EPSF = 1e-8f;
static constexpr int NIN = 1024;
static constexpr int NH  = 2048;
static constexpr int NU  = NIN + NH + 1;   // 3073

typedef __attribute__((ext_vector_type(8))) short bf16x8;
typedef __attribute__((ext_vector_type(4))) float f32x4;

// ws layout (bytes) -- MUST stay <= 16809984 (round-1 proven ws budget):
//   0       dh    2048 f32 (8 KiB)
//   8192    dhp   8 f32
//   8256    gp    1024 f32 (4 KiB, gemm grid partials)
//   12352   nrm   3 f32
//   16384   Abf   2048*2048 bf16 (8 MiB) = dh[m]*W_h[m][k]
//   8404992 Bt    2048*2048 bf16 (8 MiB) = A_prev^T
//   end 16793600
// z-partials (64*2048 f32, 512 KiB) live in d_out's A_next region (dead until k_gemm).
//
// LESSON (r8-r10): agent-scope ordered atomics inside k_gemm force L2
// writeback/invalidate -> panels evicted -> gemm 33->104us. NO atomics.
// LESSON (r11-r12): a LOAD inside a data-dependent branch can't be
// speculated/pipelined -> serial chain. Skips via ballot-compacted index
// list, loads unconditional.
// THIS ROUND (T4): K-loop uses raw s_barrier + counted s_waitcnt vmcnt(4)
// 2-deep pipeline (next tile's global_load_lds stay in flight across the
// barrier) instead of __syncthreads' full vmcnt(0) drain.

__device__ inline unsigned short f2bf(float f) {
  union { float f; unsigned u; } v; v.f = f;
  unsigned r = v.u + 0x7FFFu + ((v.u >> 16) & 1u);   // RNE
  return (unsigned short)(r >> 16);
}

__device__ inline float blockReduce256(float v, float* red) {
  int t = threadIdx.x;
  red[t] = v;
  __syncthreads();
  for (int s = 128; s > 0; s >>= 1) {
    if (t < s) red[t] += red[t + s];
    __syncthreads();
  }
  float r = red[0];
  __syncthreads();
  return r;
}

// fused stage 1 (no z-dependency):
//   blocks [0,128)     : z partials, float4; ballot-compacted nonzero coef list
//   blocks [128,1152)  : Bt[n][k] = bf16(A_prev[k][n]) 64x64 tiled transpose
//   block  1152        : norms (sumsq u, x, h_prev)
__global__ void k_stage1(const float* __restrict__ x, const float* __restrict__ hprev,
                         const float* __restrict__ Win, const float* __restrict__ Wh,
                         float* __restrict__ part,
                         const float* __restrict__ Ap, unsigned short* __restrict__ Bt,
                         const float* __restrict__ u, float* __restrict__ nrm) {
  __shared__ float ls[64][65];
  __shared__ float hl[48];
  __shared__ int   idxl[48];
  __shared__ int   cntS;
  int b = blockIdx.x;
  int t = threadIdx.x;
  if (b < 128) {
    int bj = b & 1, bi = b >> 1;
    int jc4 = bj * 256 + t;             // float4 column-group (0..511)
    int i0 = bi * 48;                   // 64*48 == 3072 == NIN+NH exactly
    if (t < 48) {
      int i = i0 + t;
      hl[t] = (i < NIN) ? x[i] : hprev[i - NIN];   // 48 parallel loads
    }
    __syncthreads();
    if (t < 64) {                       // wave 0 compacts nonzero coefficients
      bool nz = (t < 48) && (hl[t] != 0.0f);
      unsigned long long mask = __ballot(nz);
      if (nz) {
        int pos = __popcll(mask & ((1ull << t) - 1ull));
        idxl[pos] = t;
      }
      if (t == 0) cntS = __popcll(mask);
    }
    __syncthreads();
    int cnt = cntS;                     // block-uniform loop bound
    float4 s = {0.f, 0.f, 0.f, 0.f};
    for (int ii = 0; ii < cnt; ++ii) {
      int rl = idxl[ii];
      int i = i0 + rl;
      // branch selects pointer only; the load below is UNCONDITIONAL
      const float4* wrow = (i < NIN)
        ? (const float4*)Win + (size_t)i * 512
        : (const float4*)Wh  + (size_t)(i - NIN) * 512;
      float4 w = wrow[jc4];
      float cv = hl[rl];
      s.x += cv * w.x; s.y += cv * w.y; s.z += cv * w.z; s.w += cv * w.w;
    }
    ((float4*)part)[bi * 512 + jc4] = s;
  } else if (b < 1152) {
    int bb = b - 128;
    int tn = bb & 31, tk = bb >> 5;
    int r = t >> 4, c = (t & 15) * 4;
#pragma unroll
    for (int i = 0; i < 4; ++i) {
      float4 v = *(const float4*)&Ap[(size_t)(tk * 64 + r + i * 16) * NH + tn * 64 + c];
      ls[r + i * 16][c] = v.x; ls[r + i * 16][c + 1] = v.y;
      ls[r + i * 16][c + 2] = v.z; ls[r + i * 16][c + 3] = v.w;
    }
    __syncthreads();
#pragma unroll
    for (int i = 0; i < 4; ++i) {
      int n = r + i * 16;
      ushort4 o;
      o.x = f2bf(ls[c][n]);     o.y = f2bf(ls[c + 1][n]);
      o.z = f2bf(ls[c + 2][n]); o.w = f2bf(ls[c + 3][n]);
      *(ushort4*)&Bt[(size_t)(tn * 64 + n) * NH + tk * 64 + c] = o;
    }
  } else {
    float* red = (float*)ls;
    float su = 0, sx = 0, sh = 0;
    for (int i = t; i < NU;  i += 256) su += u[i] * u[i];
    for (int i = t; i < NIN; i += 256) sx += x[i] * x[i];
    for (int i = t; i < NH;  i += 256) sh += hprev[i] * hprev[i];
    float r0 = blockReduce256(su, red);
    float r1 = blockReduce256(sx, red);
    float r2 = blockReduce256(sh, red);
    if (t == 0) { nrm[0] = r0; nrm[1] = r1; nrm[2] = r2; }
  }
}

// fused: blocks [0,4096): Abf[m][k] = bf16(dh[m]*W_h[m][k]) with dh recomputed
// per block from 64 z-partials; blocks [4096,4104): z2 epilogue (h_next, dh, dhp).
__global__ void k_prep(const float* __restrict__ Wh, const float* __restrict__ part,
                       const float* __restrict__ bias,
                       unsigned short* __restrict__ Abf,
                       float* __restrict__ outh, float* __restrict__ dh,
                       float* __restrict__ dhp) {
  __shared__ float red[256];
  __shared__ float dhs;
  int b = blockIdx.x, t = threadIdx.x;
  if (b < 4096) {
    int r = b >> 1;                       // 256 float4 per block = half a 512-float4 row
    if (t < 64) red[t] = part[t * NH + r];
    __syncthreads();
    if (t == 0) {
      float z = bias[r];
      for (int i = 0; i < 64; ++i) z += red[i];
      float h = tanhf(z);
      dhs = 1.f - h * h;
    }
    __syncthreads();
    float d = dhs;
    int idx4 = b * 256 + t;               // 4096*256 == 2^20 == Wh/4 exactly
    float4 w = ((const float4*)Wh)[idx4];
    ushort4 o;
    o.x = f2bf(w.x * d); o.y = f2bf(w.y * d);
    o.z = f2bf(w.z * d); o.w = f2bf(w.w * d);
    ((ushort4*)Abf)[idx4] = o;
  } else {
    int j = (b - 4096) * 256 + t;
    float z = bias[j];
    for (int bi = 0; bi < 64; ++bi) z += part[bi * NH + j];
    float h = tanhf(z);
    outh[j] = h;
    float d = 1.f - h * h;
    dh[j] = d;
    float s = blockReduce256(d * d, red);
    if (t == 0) dhp[b - 4096] = s;
  }
}

#define GLOAD_LDS(gsrc, ldst) \
  __builtin_amdgcn_global_load_lds( \
      (const __attribute__((address_space(1))) unsigned int*)(gsrc), \
      (__attribute__((address_space(3))) unsigned int*)(ldst), 16, 0, 0)

// C[m][n] = sum_k Abf[m][k]*Bt[n][k] (= H @ A_prev), writes Hq f32 + sumsq gp.
// Core geometry unchanged (proven): 64x64 tile, BK=64, 4 waves, subtile 32x32
// (acc[2][2], 8 MFMA/step); LDS XOR swizzle kg^(row&7) both-sides (0 conflicts);
// XCD-chunked bid swizzle; grid 1024 -> 4 blocks/CU. NO atomics.
// NEW (T4): double-buffered LDS + raw s_barrier + counted vmcnt(4).
// Per iter: issue next tile's 4 gload_lds; vmcnt(4) waits only CURRENT tile's
// 4 oldest loads (next's stay in flight across the barrier); barrier; compute;
// barrier (guards overwrite). No vmcnt(0) drain in the loop.
__global__ __launch_bounds__(256) void k_gemm(const unsigned short* __restrict__ Abf,
                                              const unsigned short* __restrict__ Bt,
                                              float* __restrict__ Hq,
                                              float* __restrict__ gp) {
  __shared__ unsigned short As[2][4096];   // per buf: 64 rows x 8 granules x 16B = 8KB
  __shared__ unsigned short Bs[2][4096];
  __shared__ float red[256];
  const int K = NH;
  int t = threadIdx.x;
  int lane = t & 63;
  int bid = blockIdx.x;
  int swz = (bid & 7) * 128 + (bid >> 3);   // XCD-chunked, bijective on [0,1024)
  int bm = swz >> 5, bn = swz & 31;
  int wid = t >> 6;
  int wr = wid >> 1, wc = wid & 1;

  int srow = t >> 3, skg = t & 7;
  int sxg = skg ^ (srow & 7);
  const unsigned short* AgBase = Abf + (size_t)(bm * 64 + srow) * K + sxg * 8;
  const unsigned short* BgBase = Bt  + (size_t)(bn * 64 + srow) * K + sxg * 8;

#define STAGE(buf, k0)                                                  \
  do {                                                                  \
    GLOAD_LDS(AgBase + (k0),          &As[buf][0] + t * 8);             \
    GLOAD_LDS(AgBase + 32 * K + (k0), &As[buf][0] + (t + 256) * 8);     \
    GLOAD_LDS(BgBase + (k0),          &Bs[buf][0] + t * 8);             \
    GLOAD_LDS(BgBase + 32 * K + (k0), &Bs[buf][0] + (t + 256) * 8);     \
  } while (0)

  f32x4 acc[2][2] = {};

  STAGE(0, 0);
  int buf = 0;
  for (int tt = 0; tt < 32; ++tt) {
    if (tt < 31) {
      STAGE(buf ^ 1, (tt + 1) * 64);            // next tile: 4 loads in flight
      asm volatile("s_waitcnt vmcnt(4)" ::: "memory");   // current tile's 4 oldest done
    } else {
      asm volatile("s_waitcnt vmcnt(0)" ::: "memory");
    }
    __builtin_amdgcn_s_barrier();               // all waves waited their own loads
    __builtin_amdgcn_sched_barrier(0);          // rule #18: pin reads below
    __builtin_amdgcn_s_setprio(1);
#pragma unroll
    for (int kk = 0; kk < 2; ++kk) {
      bf16x8 af[2], bfr[2];
#pragma unroll
      for (int mi = 0; mi < 2; ++mi) {
        int row = wr * 32 + mi * 16 + (lane & 15);
        int kg = (kk * 4 + (lane >> 4)) ^ (row & 7);
        af[mi] = *(const bf16x8*)&As[buf][(row * 8 + kg) * 8];
      }
#pragma unroll
      for (int ni = 0; ni < 2; ++ni) {
        int row = wc * 32 + ni * 16 + (lane & 15);
        int kg = (kk * 4 + (lane >> 4)) ^ (row & 7);
        bfr[ni] = *(const bf16x8*)&Bs[buf][(row * 8 + kg) * 8];
      }
#pragma unroll
      for (int mi = 0; mi < 2; ++mi)
#pragma unroll
        for (int ni = 0; ni < 2; ++ni)
          acc[mi][ni] = __builtin_amdgcn_mfma_f32_16x16x32_bf16(af[mi], bfr[ni], acc[mi][ni], 0, 0, 0);
    }
    __builtin_amdgcn_s_setprio(0);
    asm volatile("s_waitcnt lgkmcnt(0)" ::: "memory");  // reads of buf complete
    __builtin_amdgcn_s_barrier();               // safe to overwrite buf next iter
    buf ^= 1;
  }
#undef STAGE

  float ss = 0.f;
  int r0 = bm * 64 + wr * 32 + (lane >> 4) * 4;
  int c0 = bn * 64 + wc * 32 + (lane & 15);
#pragma unroll
  for (int mi = 0; mi < 2; ++mi)
#pragma unroll
    for (int r = 0; r < 4; ++r) {
      int row = r0 + mi * 16 + r;
#pragma unroll
      for (int ni = 0; ni < 2; ++ni) {
        float v = acc[mi][ni][r];
        Hq[(size_t)row * NH + c0 + ni * 16] = v;
        ss += v * v;
      }
    }
  float s = blockReduce256(ss, red);
  if (t == 0) gp[blockIdx.x] = s;
}

// blocks [0,2048): A_next = cf2*Hq (+ diag cf3*dh) in place, float4.
// blocks [2048,2061): u_next.
// Every block re-reduces gp[1024] + dhp + nrm and computes coef inline
// (identical fixed-order arithmetic per block -> deterministic; L2-hot).
__global__ void k_Au(float* __restrict__ Hq, const float* __restrict__ dh,
                     const float* __restrict__ gp, const float* __restrict__ dhp,
                     const float* __restrict__ nrm,
                     const float* __restrict__ u, const float* __restrict__ x,
                     const float* __restrict__ hprev, float* __restrict__ outu) {
  __shared__ float red[256];
  __shared__ float cf[4];
  int t = threadIdx.x;
  float s = blockReduce256(gp[t] + gp[t + 256] + gp[t + 512] + gp[t + 768], red);
  if (t == 0) {
    float sdh = 0;
    for (int i = 0; i < 8; ++i) sdh += dhp[i];
    float nu  = sqrtf(nrm[0]);
    float nhq = sqrtf(nrm[1] + nrm[2] + 1.0f);
    float ndh = sqrtf(sdh);
    float nHq = sqrtf(s);
    float p1 = sqrtf(nHq / (EPSF + nu));
    float p2 = sqrtf(ndh / (EPSF + nhq));
    cf[0] = C1 * p1;
    cf[1] = C2 * p2;
    cf[2] = C1 / (p1 + EPSF);
    cf[3] = C2 / (p2 + EPSF);
  }
  __syncthreads();

  if (blockIdx.x >= 2048) {
    int i = (blockIdx.x - 2048) * 256 + t;
    if (i < NU) {
      float hq = (i < NIN) ? x[i] : (i < NIN + NH ? hprev[i - NIN] : 1.0f);
      outu[i] = cf[0] * u[i] + cf[1] * hq;
    }
    return;
  }
  float sA = cf[2], sD = cf[3];
  float4* H4 = (float4*)Hq;
  // 2048 blocks * 256 thr * 2 iters == 2^20 float4 == NH*NH/4 exactly
  int i4 = blockIdx.x * 256 + t;
#pragma unroll
  for (int it = 0; it < 2; ++it, i4 += 2048 * 256) {
    float4 v = H4[i4];
    v.x *= sA; v.y *= sA; v.z *= sA; v.w *= sA;
    int row = i4 >> 9;                 // 512 float4 per row
    int c = (i4 & 511) * 4;
    int j = row - c;
    if (j >= 0 && j < 4) {
      float add = sD * dh[row];
      if (j == 0) v.x += add; else if (j == 1) v.y += add;
      else if (j == 2) v.z += add; else v.w += add;
    }
    H4[i4] = v;
  }
}

extern "C" void kernel_launch(void* const* d_in, const int* in_sizes, int n_in,
                              void* d_out, int out_size, void* d_ws, size_t ws_size,
                              hipStream_t stream) {
  const float* x     = (const float*)d_in[0];
  const float* hprev = (const float*)d_in[1];
  const float* Win   = (const float*)d_in[2];
  const float* Wh    = (const float*)d_in[3];
  const float* bias  = (const float*)d_in[4];
  const float* uprev = (const float*)d_in[5];
  const float* Ap    = (const float*)d_in[6];

  float* out  = (float*)d_out;
  float* outh = out;                 // [2048]
  float* outu = out + NH;            // [3073]
  float* Hq   = out + NH + NU;       // [2048*2048] (in-place scaled to A_next)
  float* part = Hq;                  // z-partials (512KB) borrow region (dead until k_gemm)

  char* ws = (char*)d_ws;
  float* dh   = (float*)ws;
  float* dhp  = (float*)(ws + 8192);
  float* gp   = (float*)(ws + 8256);
  float* nrm  = (float*)(ws + 12352);
  unsigned short* Abf = (unsigned short*)(ws + 16384);
  unsigned short* Bt  = (unsigned short*)(ws + 8404992);

  k_stage1 <<<1153, 256, 0, stream>>>(x, hprev, Win, Wh, part, Ap, Bt, uprev, nrm);
  k_prep   <<<4104, 256, 0, stream>>>(Wh, part, bias, Abf, outh, dh, dhp);
  k_gemm   <<<1024, 256, 0, stream>>>(Abf, Bt, Hq, gp);
  k_Au     <<<2061, 256, 0, stream>>>(Hq, dh, gp, dhp, nrm, uprev, x, hprev, outu);
}

// Round 16
// 58.174 us; speedup vs baseline: 1.0621x; 1.0621x over previous
//
#include <hip/hip_runtime.h>
#include <hip/hip_bf16.h>
#include <math.h>

// signs c1,c2 decoded in round 0/1: both +1 (absmax 0.0078 = bf16 noise)
#define C1 1.0f
#define C2 1.0f

static constexpr float EPSF = 1e-8f;
static constexpr int NIN = 1024;
static constexpr int NH  = 2048;
static constexpr int NU  = NIN + NH + 1;   // 3073

typedef __attribute__((ext_vector_type(8))) short bf16x8;
typedef __attribute__((ext_vector_type(4))) float f32x4;

// ws layout (bytes) -- MUST stay <= 16809984 (round-1 proven ws budget):
//   0       dh    2048 f32 (8 KiB)  -- written by gemm bn==0 blocks
//   8192    gp    1024 f32 (4 KiB, gemm sumsq partials)
//   12288   gp2   32 f32 (per-bm sum dh^2 partials)
//   12416   nrm   3 f32
//   16384   Whbf  2048*2048 bf16 (8 MiB) = bf16(W_h)   [dh applied in gemm epilogue]
//   8404992 Bt    2048*2048 bf16 (8 MiB) = A_prev^T
//   end 16793600
// z-partials (64*2048 f32, 512 KiB) live in the TAIL of d_out's A_next region
// (rows 1984-2047): those rows are written only by bm==31 gemm blocks in their
// EPILOGUE; all gemm prologues read part within ~1us of dispatch (grid 1024 =
// 4/CU, capacity 8/CU -> all blocks co-resident from t=0), epilogues start
// >25us later. __launch_bounds__(256) + grid<=capacity per guide §1.
//
// LESSON (r8-r10): agent-scope ordered atomics inside k_gemm force L2
// writeback/invalidate -> 3x slowdown. NO atomics anywhere.
// LESSON (r11-r12): loads inside data-dependent branches serialize; skips via
// ballot-compacted index list, loads unconditional.
// LESSON (r15): counted-vmcnt pipeline null on 2-phase loop (T4 regime gate);
// plain __syncthreads loop kept.

__device__ inline unsigned short f2bf(float f) {
  union { float f; unsigned u; } v; v.f = f;
  unsigned r = v.u + 0x7FFFu + ((v.u >> 16) & 1u);   // RNE
  return (unsigned short)(r >> 16);
}

__device__ inline float blockReduce256(float v, float* red) {
  int t = threadIdx.x;
  red[t] = v;
  __syncthreads();
  for (int s = 128; s > 0; s >>= 1) {
    if (t < s) red[t] += red[t + s];
    __syncthreads();
  }
  float r = red[0];
  __syncthreads();
  return r;
}

// fused stage 1 (everything with no z-dependency):
//   blocks [0,128)     : z partials, float4; ballot-compacted nonzero coef list
//   blocks [128,1152)  : Bt[n][k] = bf16(A_prev[k][n]) 64x64 tiled transpose
//   blocks [1152,5248) : Whbf = bf16(W_h) straight conversion (no dh)
//   block  5248        : norms (sumsq u, x, h_prev)
__global__ void k_stage1(const float* __restrict__ x, const float* __restrict__ hprev,
                         const float* __restrict__ Win, const float* __restrict__ Wh,
                         float* __restrict__ part,
                         const float* __restrict__ Ap, unsigned short* __restrict__ Bt,
                         unsigned short* __restrict__ Whbf,
                         const float* __restrict__ u, float* __restrict__ nrm) {
  __shared__ float ls[64][65];
  __shared__ float hl[48];
  __shared__ int   idxl[48];
  __shared__ int   cntS;
  int b = blockIdx.x;
  int t = threadIdx.x;
  if (b < 128) {
    int bj = b & 1, bi = b >> 1;
    int jc4 = bj * 256 + t;             // float4 column-group (0..511)
    int i0 = bi * 48;                   // 64*48 == 3072 == NIN+NH exactly
    if (t < 48) {
      int i = i0 + t;
      hl[t] = (i < NIN) ? x[i] : hprev[i - NIN];   // 48 parallel loads
    }
    __syncthreads();
    if (t < 64) {                       // wave 0 compacts nonzero coefficients
      bool nz = (t < 48) && (hl[t] != 0.0f);
      unsigned long long mask = __ballot(nz);
      if (nz) {
        int pos = __popcll(mask & ((1ull << t) - 1ull));
        idxl[pos] = t;
      }
      if (t == 0) cntS = __popcll(mask);
    }
    __syncthreads();
    int cnt = cntS;                     // block-uniform loop bound
    float4 s = {0.f, 0.f, 0.f, 0.f};
    for (int ii = 0; ii < cnt; ++ii) {
      int rl = idxl[ii];
      int i = i0 + rl;
      // branch selects pointer only; the load below is UNCONDITIONAL
      const float4* wrow = (i < NIN)
        ? (const float4*)Win + (size_t)i * 512
        : (const float4*)Wh  + (size_t)(i - NIN) * 512;
      float4 w = wrow[jc4];
      float cv = hl[rl];
      s.x += cv * w.x; s.y += cv * w.y; s.z += cv * w.z; s.w += cv * w.w;
    }
    ((float4*)part)[bi * 512 + jc4] = s;
  } else if (b < 1152) {
    int bb = b - 128;
    int tn = bb & 31, tk = bb >> 5;
    int r = t >> 4, c = (t & 15) * 4;
#pragma unroll
    for (int i = 0; i < 4; ++i) {
      float4 v = *(const float4*)&Ap[(size_t)(tk * 64 + r + i * 16) * NH + tn * 64 + c];
      ls[r + i * 16][c] = v.x; ls[r + i * 16][c + 1] = v.y;
      ls[r + i * 16][c + 2] = v.z; ls[r + i * 16][c + 3] = v.w;
    }
    __syncthreads();
#pragma unroll
    for (int i = 0; i < 4; ++i) {
      int n = r + i * 16;
      ushort4 o;
      o.x = f2bf(ls[c][n]);     o.y = f2bf(ls[c + 1][n]);
      o.z = f2bf(ls[c + 2][n]); o.w = f2bf(ls[c + 3][n]);
      *(ushort4*)&Bt[(size_t)(tn * 64 + n) * NH + tk * 64 + c] = o;
    }
  } else if (b < 5248) {
    int idx4 = (b - 1152) * 256 + t;    // 4096*256 == 2^20 == Wh/4 exactly
    float4 w = ((const float4*)Wh)[idx4];
    ushort4 o;
    o.x = f2bf(w.x); o.y = f2bf(w.y);
    o.z = f2bf(w.z); o.w = f2bf(w.w);
    ((ushort4*)Whbf)[idx4] = o;
  } else {
    float* red = (float*)ls;
    float su = 0, sx = 0, sh = 0;
    for (int i = t; i < NU;  i += 256) su += u[i] * u[i];
    for (int i = t; i < NIN; i += 256) sx += x[i] * x[i];
    for (int i = t; i < NH;  i += 256) sh += hprev[i] * hprev[i];
    float r0 = blockReduce256(su, red);
    float r1 = blockReduce256(sx, red);
    float r2 = blockReduce256(sh, red);
    if (t == 0) { nrm[0] = r0; nrm[1] = r1; nrm[2] = r2; }
  }
}

#define GLOAD_LDS(gsrc, ldst) \
  __builtin_amdgcn_global_load_lds( \
      (const __attribute__((address_space(1))) unsigned int*)(gsrc), \
      (__attribute__((address_space(3))) unsigned int*)(ldst), 16, 0, 0)

// Hq[m][n] = dh[m] * sum_k Whbf[m][k]*Bt[n][k] (= diag(dh) W_h A_prev).
// PROVEN r14 CORE (64x64 tile, BK=64, 4 waves, acc[2][2], XOR-swizzled LDS,
// XCD-chunked bid swizzle, grid 1024 -> 4/CU, plain __syncthreads, no atomics).
// NEW prologue: threads<64 compute dh for the block's 64 A-rows from the
// z-partials (part, L2-hot) + bias; bn==0 blocks also write h_next, ws dh[],
// and gp2[bm] = sum dh^2 (unique writers). Epilogue scales acc by dh[row] (f32)
// before store + sumsq.
__global__ __launch_bounds__(256) void k_gemm(const unsigned short* __restrict__ Whbf,
                                              const unsigned short* __restrict__ Bt,
                                              const float* __restrict__ part,
                                              const float* __restrict__ bias,
                                              float* __restrict__ Hq,
                                              float* __restrict__ gp,
                                              float* __restrict__ gp2,
                                              float* __restrict__ dhw,
                                              float* __restrict__ outh) {
  __shared__ unsigned short As[512 * 8];   // 64 rows x 8 granules x 16B = 8KB
  __shared__ unsigned short Bs[512 * 8];
  __shared__ float red[256];
  __shared__ float dhl[64];
  const int K = NH;
  int t = threadIdx.x;
  int lane = t & 63;
  int bid = blockIdx.x;
  int swz = (bid & 7) * 128 + (bid >> 3);   // XCD-chunked, bijective on [0,1024)
  int bm = swz >> 5, bn = swz & 31;
  int wid = t >> 6;
  int wr = wid >> 1, wc = wid & 1;

  // ---- prologue: dh for this block's 64 rows (reads part BEFORE any Hq write;
  // all 1024 blocks co-resident -> prologues precede all epilogues) ----
  float dd = 0.f;
  if (t < 64) {
    int row = bm * 64 + t;
    float z = bias[row];
    for (int s2 = 0; s2 < 64; ++s2) z += part[s2 * NH + row];   // coalesced 256B/slice
    float h = tanhf(z);
    dd = 1.f - h * h;
    dhl[t] = dd;
    if (bn == 0) { outh[row] = h; dhw[row] = dd; }
  }
  if (bn == 0) {
    float s2r = blockReduce256((t < 64) ? dd * dd : 0.f, red);
    if (t == 0) gp2[bm] = s2r;
  }

  int srow = t >> 3, skg = t & 7;
  int sxg = skg ^ (srow & 7);
  const unsigned short* AgBase = Whbf + (size_t)(bm * 64 + srow) * K + sxg * 8;
  const unsigned short* BgBase = Bt   + (size_t)(bn * 64 + srow) * K + sxg * 8;

  f32x4 acc[2][2] = {};

  for (int k0 = 0; k0 < K; k0 += 64) {
    GLOAD_LDS(AgBase + k0,          As + t * 8);
    GLOAD_LDS(AgBase + 32 * K + k0, As + (t + 256) * 8);
    GLOAD_LDS(BgBase + k0,          Bs + t * 8);
    GLOAD_LDS(BgBase + 32 * K + k0, Bs + (t + 256) * 8);
    __syncthreads();
    __builtin_amdgcn_s_setprio(1);
#pragma unroll
    for (int kk = 0; kk < 2; ++kk) {
      bf16x8 af[2], bfr[2];
#pragma unroll
      for (int mi = 0; mi < 2; ++mi) {
        int row = wr * 32 + mi * 16 + (lane & 15);
        int kg = (kk * 4 + (lane >> 4)) ^ (row & 7);
        af[mi] = *(const bf16x8*)&As[(row * 8 + kg) * 8];
      }
#pragma unroll
      for (int ni = 0; ni < 2; ++ni) {
        int row = wc * 32 + ni * 16 + (lane & 15);
        int kg = (kk * 4 + (lane >> 4)) ^ (row & 7);
        bfr[ni] = *(const bf16x8*)&Bs[(row * 8 + kg) * 8];
      }
#pragma unroll
      for (int mi = 0; mi < 2; ++mi)
#pragma unroll
        for (int ni = 0; ni < 2; ++ni)
          acc[mi][ni] = __builtin_amdgcn_mfma_f32_16x16x32_bf16(af[mi], bfr[ni], acc[mi][ni], 0, 0, 0);
    }
    __builtin_amdgcn_s_setprio(0);
    __syncthreads();
  }

  float ss = 0.f;
  int r0 = bm * 64 + wr * 32 + (lane >> 4) * 4;
  int c0 = bn * 64 + wc * 32 + (lane & 15);
#pragma unroll
  for (int mi = 0; mi < 2; ++mi)
#pragma unroll
    for (int r = 0; r < 4; ++r) {
      int row = r0 + mi * 16 + r;
      float dv = dhl[wr * 32 + (lane >> 4) * 4 + mi * 16 + r];   // dh[row], f32
#pragma unroll
      for (int ni = 0; ni < 2; ++ni) {
        float v = dv * acc[mi][ni][r];
        Hq[(size_t)row * NH + c0 + ni * 16] = v;
        ss += v * v;
      }
    }
  float s = blockReduce256(ss, red);
  if (t == 0) gp[bid] = s;
}

// blocks [0,2048): A_next = cf2*Hq (+ diag cf3*dh) in place, float4.
// blocks [2048,2061): u_next.
// Every block re-reduces gp[1024] + gp2[32] + nrm, computes coef inline
// (identical fixed-order arithmetic per block -> deterministic; L2-hot).
__global__ void k_Au(float* __restrict__ Hq, const float* __restrict__ dh,
                     const float* __restrict__ gp, const float* __restrict__ gp2,
                     const float* __restrict__ nrm,
                     const float* __restrict__ u, const float* __restrict__ x,
                     const float* __restrict__ hprev, float* __restrict__ outu) {
  __shared__ float red[256];
  __shared__ float cf[4];
  int t = threadIdx.x;
  float s = blockReduce256(gp[t] + gp[t + 256] + gp[t + 512] + gp[t + 768], red);
  if (t == 0) {
    float sdh = 0;
    for (int i = 0; i < 32; ++i) sdh += gp2[i];
    float nu  = sqrtf(nrm[0]);
    float nhq = sqrtf(nrm[1] + nrm[2] + 1.0f);
    float ndh = sqrtf(sdh);
    float nHq = sqrtf(s);
    float p1 = sqrtf(nHq / (EPSF + nu));
    float p2 = sqrtf(ndh / (EPSF + nhq));
    cf[0] = C1 * p1;
    cf[1] = C2 * p2;
    cf[2] = C1 / (p1 + EPSF);
    cf[3] = C2 / (p2 + EPSF);
  }
  __syncthreads();

  if (blockIdx.x >= 2048) {
    int i = (blockIdx.x - 2048) * 256 + t;
    if (i < NU) {
      float hq = (i < NIN) ? x[i] : (i < NIN + NH ? hprev[i - NIN] : 1.0f);
      outu[i] = cf[0] * u[i] + cf[1] * hq;
    }
    return;
  }
  float sA = cf[2], sD = cf[3];
  float4* H4 = (float4*)Hq;
  // 2048 blocks * 256 thr * 2 iters == 2^20 float4 == NH*NH/4 exactly
  int i4 = blockIdx.x * 256 + t;
#pragma unroll
  for (int it = 0; it < 2; ++it, i4 += 2048 * 256) {
    float4 v = H4[i4];
    v.x *= sA; v.y *= sA; v.z *= sA; v.w *= sA;
    int row = i4 >> 9;                 // 512 float4 per row
    int c = (i4 & 511) * 4;
    int j = row - c;
    if (j >= 0 && j < 4) {
      float add = sD * dh[row];
      if (j == 0) v.x += add; else if (j == 1) v.y += add;
      else if (j == 2) v.z += add; else v.w += add;
    }
    H4[i4] = v;
  }
}

extern "C" void kernel_launch(void* const* d_in, const int* in_sizes, int n_in,
                              void* d_out, int out_size, void* d_ws, size_t ws_size,
                              hipStream_t stream) {
  const float* x     = (const float*)d_in[0];
  const float* hprev = (const float*)d_in[1];
  const float* Win   = (const float*)d_in[2];
  const float* Wh    = (const float*)d_in[3];
  const float* bias  = (const float*)d_in[4];
  const float* uprev = (const float*)d_in[5];
  const float* Ap    = (const float*)d_in[6];

  float* out  = (float*)d_out;
  float* outh = out;                 // [2048]
  float* outu = out + NH;            // [3073]
  float* Hq   = out + NH + NU;       // [2048*2048] (in-place scaled to A_next)
  float* part = Hq + (size_t)(NH - 64) * NH;   // z-partials in TAIL rows 1984-2047

  char* ws = (char*)d_ws;
  float* dh   = (float*)ws;
  float* gp   = (float*)(ws + 8192);
  float* gp2  = (float*)(ws + 12288);
  float* nrm  = (float*)(ws + 12416);
  unsigned short* Whbf = (unsigned short*)(ws + 16384);
  unsigned short* Bt   = (unsigned short*)(ws + 8404992);

  k_stage1 <<<5249, 256, 0, stream>>>(x, hprev, Win, Wh, part, Ap, Bt, Whbf, uprev, nrm);
  k_gemm   <<<1024, 256, 0, stream>>>(Whbf, Bt, part, bias, Hq, gp, gp2, dh, outh);
  k_Au     <<<2061, 256, 0, stream>>>(Hq, dh, gp, gp2, nrm, uprev, x, hprev, outu);
}